// Round 10
// baseline (23.876 us; speedup 1.0000x reference)
//
#include <hip/hip_runtime.h>

#define NB 4   // BATCH

typedef float f32x4 __attribute__((ext_vector_type(4)));

__global__ __launch_bounds__(256) void render_cov2d_kernel(
    const int*   __restrict__ indexes,   // [NB]
    const float* __restrict__ xyz,       // [N,3]
    const float* __restrict__ scales,    // [N,3]
    const float* __restrict__ quats,     // [N,4]
    const float* __restrict__ tf,        // [8,4,4]
    const float* __restrict__ focal,     // [8,2]
    const float* __restrict__ widths,    // [8]
    float*       __restrict__ out,       // [NB,N,2,2]
    int N)
{
    __shared__ float s_xyz[768];   // 256 gaussians * 3
    __shared__ float s_sc [768];

    const int tid    = threadIdx.x;
    const int base_g = blockIdx.x * 256;

    // one VMEM load for all four camera indexes, then force SGPR-uniform
    const int4 idx4 = *reinterpret_cast<const int4*>(indexes);
    int cam_s[NB];
    cam_s[0] = __builtin_amdgcn_readfirstlane(idx4.x);
    cam_s[1] = __builtin_amdgcn_readfirstlane(idx4.y);
    cam_s[2] = __builtin_amdgcn_readfirstlane(idx4.z);
    cam_s[3] = __builtin_amdgcn_readfirstlane(idx4.w);

    // ---- cooperative coalesced staging of xyz & scales into LDS (NT loads) ----
    if (base_g + 256 <= N) {
        const f32x4* xin = reinterpret_cast<const f32x4*>(xyz    + (size_t)base_g*3);
        const f32x4* sin_ = reinterpret_cast<const f32x4*>(scales + (size_t)base_g*3);
        if (tid < 192) {
            f32x4 xv = __builtin_nontemporal_load(xin + tid);
            f32x4 sv = __builtin_nontemporal_load(sin_ + tid);
            reinterpret_cast<f32x4*>(s_xyz)[tid] = xv;
            reinterpret_cast<f32x4*>(s_sc )[tid] = sv;
        }
    } else {
        const size_t lim = (size_t)N * 3;
        for (int i = tid; i < 768; i += 256) {
            size_t gi = (size_t)base_g*3 + i;
            s_xyz[i] = (gi < lim) ? xyz[gi]    : 1.f;
            s_sc [i] = (gi < lim) ? scales[gi] : 1.f;
        }
    }
    __syncthreads();

    const int n = base_g + tid;
    if (n >= N) return;

    const float px = s_xyz[3*tid+0], py = s_xyz[3*tid+1], pz = s_xyz[3*tid+2];
    const float sx = s_sc [3*tid+0], sy = s_sc [3*tid+1], sz = s_sc [3*tid+2];

    // ---- quat -> rotmat -> cov3d (6 uniques) ----
    f32x4 q = __builtin_nontemporal_load(
        reinterpret_cast<const f32x4*>(quats + 4*(size_t)n));
    float qn = rsqrtf(q.x*q.x + q.y*q.y + q.z*q.z + q.w*q.w);
    float r = q.x*qn, x = q.y*qn, y = q.z*qn, z = q.w*qn;
    float R00 = 1.f - 2.f*(y*y + z*z), R01 = 2.f*(x*y - r*z), R02 = 2.f*(x*z + r*y);
    float R10 = 2.f*(x*y + r*z), R11 = 1.f - 2.f*(x*x + z*z), R12 = 2.f*(y*z - r*x);
    float R20 = 2.f*(x*z - r*y), R21 = 2.f*(y*z + r*x), R22 = 1.f - 2.f*(x*x + y*y);

    float L00=R00*sx, L01=R01*sy, L02=R02*sz;
    float L10=R10*sx, L11=R11*sy, L12=R12*sz;
    float L20=R20*sx, L21=R21*sy, L22=R22*sz;

    float C00 = L00*L00 + L01*L01 + L02*L02;
    float C01 = L00*L10 + L01*L11 + L02*L12;
    float C02 = L00*L20 + L01*L21 + L02*L22;
    float C11 = L10*L10 + L11*L11 + L12*L12;
    float C12 = L10*L20 + L11*L21 + L12*L22;
    float C22 = L20*L20 + L21*L21 + L22*L22;

    #pragma unroll
    for (int b = 0; b < NB; ++b) {
        const int cam = cam_s[b];           // SGPR-uniform -> scalar loads
        const float* T4 = tf + cam*16;
        float A00=T4[0], A01=T4[1], A02=T4[2],  t0=T4[3];
        float A10=T4[4], A11=T4[5], A12=T4[6],  t1=T4[7];
        float A20=T4[8], A21=T4[9], A22=T4[10], t2=T4[11];
        float fx = focal[cam*2+0], fy = focal[cam*2+1];
        float wid = widths[cam];
        float limx = 0.65f * wid / fx;
        float limy = 0.65f * wid / fy;

        float mx = A00*px + A01*py + A02*pz + t0;
        float my = A10*px + A11*py + A12*pz + t1;
        float mz = A20*px + A21*py + A22*pz + t2;

        float invz = 1.f / mz;
        float cx = fminf(fmaxf(mx*invz, -limx), limx) * mz;
        float cy = fminf(fmaxf(my*invz, -limy), limy) * mz;

        float a0 = fx * invz;
        float a2 = -fx * cx * invz * invz;
        float b1 = fy * invz;
        float b2 = -fy * cy * invz * invz;

        float T00 = a0*A00 + a2*A20;
        float T01 = a0*A01 + a2*A21;
        float T02 = a0*A02 + a2*A22;
        float T10 = b1*A10 + b2*A20;
        float T11 = b1*A11 + b2*A21;
        float T12 = b1*A12 + b2*A22;

        float M00 = T00*C00 + T01*C01 + T02*C02;
        float M01 = T00*C01 + T01*C11 + T02*C12;
        float M02 = T00*C02 + T01*C12 + T02*C22;
        float M10 = T10*C00 + T11*C01 + T12*C02;
        float M11 = T10*C01 + T11*C11 + T12*C12;
        float M12 = T10*C02 + T11*C12 + T12*C22;

        float o00 = M00*T00 + M01*T01 + M02*T02;
        float o01 = M00*T10 + M01*T11 + M02*T12;
        float o11 = M10*T10 + M11*T11 + M12*T12;

        f32x4 v = { o00, o01, o01, o11 };
        __builtin_nontemporal_store(v,
            reinterpret_cast<f32x4*>(out + ((size_t)b*N + n)*4));
    }
}

extern "C" void kernel_launch(void* const* d_in, const int* in_sizes, int n_in,
                              void* d_out, int out_size, void* d_ws, size_t ws_size,
                              hipStream_t stream) {
    const int*   indexes = (const int*)  d_in[0];
    const float* xyz     = (const float*)d_in[1];
    const float* scales  = (const float*)d_in[2];
    const float* quats   = (const float*)d_in[3];
    const float* tf      = (const float*)d_in[4];
    const float* focal   = (const float*)d_in[5];
    const float* widths  = (const float*)d_in[6];
    float*       out     = (float*)d_out;

    int N = in_sizes[1] / 3;   // N_GAUSS
    int block = 256;
    int grid = (N + block - 1) / block;
    render_cov2d_kernel<<<grid, block, 0, stream>>>(
        indexes, xyz, scales, quats, tf, focal, widths, out, N);
}

// Round 11
// 22.117 us; speedup vs baseline: 1.0795x; 1.0795x over previous
//
#include <hip/hip_runtime.h>

#define NB 4   // BATCH

typedef float f32x4 __attribute__((ext_vector_type(4)));

__global__ __launch_bounds__(256) void render_cov2d_kernel(
    const int*   __restrict__ indexes,   // [NB]
    const float* __restrict__ xyz,       // [N,3]
    const float* __restrict__ scales,    // [N,3]
    const float* __restrict__ quats,     // [N,4]
    const float* __restrict__ tf,        // [8,4,4]
    const float* __restrict__ focal,     // [8,2]
    const float* __restrict__ widths,    // [8]
    float*       __restrict__ out,       // [NB,N,2,2]
    int N)
{
    __shared__ float s_xyz[768];   // 256 gaussians * 3
    __shared__ float s_sc [768];

    const int tid    = threadIdx.x;
    const int base_g = blockIdx.x * 256;

    // one VMEM load for all four camera indexes, then force SGPR-uniform
    const int4 idx4 = *reinterpret_cast<const int4*>(indexes);
    int cam_s[NB];
    cam_s[0] = __builtin_amdgcn_readfirstlane(idx4.x);
    cam_s[1] = __builtin_amdgcn_readfirstlane(idx4.y);
    cam_s[2] = __builtin_amdgcn_readfirstlane(idx4.z);
    cam_s[3] = __builtin_amdgcn_readfirstlane(idx4.w);

    // ---- cooperative coalesced staging of xyz & scales into LDS ----
    if (base_g + 256 <= N) {
        const float4* xin = reinterpret_cast<const float4*>(xyz    + (size_t)base_g*3);
        const float4* sin_ = reinterpret_cast<const float4*>(scales + (size_t)base_g*3);
        if (tid < 192) {
            reinterpret_cast<float4*>(s_xyz)[tid] = xin[tid];
            reinterpret_cast<float4*>(s_sc )[tid] = sin_[tid];
        }
    } else {
        const size_t lim = (size_t)N * 3;
        for (int i = tid; i < 768; i += 256) {
            size_t gi = (size_t)base_g*3 + i;
            s_xyz[i] = (gi < lim) ? xyz[gi]    : 1.f;
            s_sc [i] = (gi < lim) ? scales[gi] : 1.f;
        }
    }
    __syncthreads();

    const int n = base_g + tid;
    if (n >= N) return;

    const float px = s_xyz[3*tid+0], py = s_xyz[3*tid+1], pz = s_xyz[3*tid+2];
    const float sx = s_sc [3*tid+0], sy = s_sc [3*tid+1], sz = s_sc [3*tid+2];

    // ---- quat -> rotmat -> cov3d (6 uniques) ----
    float4 q = *reinterpret_cast<const float4*>(quats + 4*(size_t)n);
    float qn = rsqrtf(q.x*q.x + q.y*q.y + q.z*q.z + q.w*q.w);
    float r = q.x*qn, x = q.y*qn, y = q.z*qn, z = q.w*qn;
    float R00 = 1.f - 2.f*(y*y + z*z), R01 = 2.f*(x*y - r*z), R02 = 2.f*(x*z + r*y);
    float R10 = 2.f*(x*y + r*z), R11 = 1.f - 2.f*(x*x + z*z), R12 = 2.f*(y*z - r*x);
    float R20 = 2.f*(x*z - r*y), R21 = 2.f*(y*z + r*x), R22 = 1.f - 2.f*(x*x + y*y);

    float L00=R00*sx, L01=R01*sy, L02=R02*sz;
    float L10=R10*sx, L11=R11*sy, L12=R12*sz;
    float L20=R20*sx, L21=R21*sy, L22=R22*sz;

    float C00 = L00*L00 + L01*L01 + L02*L02;
    float C01 = L00*L10 + L01*L11 + L02*L12;
    float C02 = L00*L20 + L01*L21 + L02*L22;
    float C11 = L10*L10 + L11*L11 + L12*L12;
    float C12 = L10*L20 + L11*L21 + L12*L22;
    float C22 = L20*L20 + L21*L21 + L22*L22;

    #pragma unroll
    for (int b = 0; b < NB; ++b) {
        const int cam = cam_s[b];           // SGPR-uniform -> scalar loads
        const float* T4 = tf + cam*16;
        float A00=T4[0], A01=T4[1], A02=T4[2],  t0=T4[3];
        float A10=T4[4], A11=T4[5], A12=T4[6],  t1=T4[7];
        float A20=T4[8], A21=T4[9], A22=T4[10], t2=T4[11];
        float fx = focal[cam*2+0], fy = focal[cam*2+1];
        float wid = widths[cam];
        float limx = 0.65f * wid / fx;
        float limy = 0.65f * wid / fy;

        float mx = A00*px + A01*py + A02*pz + t0;
        float my = A10*px + A11*py + A12*pz + t1;
        float mz = A20*px + A21*py + A22*pz + t2;

        float invz = 1.f / mz;
        float cx = fminf(fmaxf(mx*invz, -limx), limx) * mz;
        float cy = fminf(fmaxf(my*invz, -limy), limy) * mz;

        float a0 = fx * invz;
        float a2 = -fx * cx * invz * invz;
        float b1 = fy * invz;
        float b2 = -fy * cy * invz * invz;

        float T00 = a0*A00 + a2*A20;
        float T01 = a0*A01 + a2*A21;
        float T02 = a0*A02 + a2*A22;
        float T10 = b1*A10 + b2*A20;
        float T11 = b1*A11 + b2*A21;
        float T12 = b1*A12 + b2*A22;

        float M00 = T00*C00 + T01*C01 + T02*C02;
        float M01 = T00*C01 + T01*C11 + T02*C12;
        float M02 = T00*C02 + T01*C12 + T02*C22;
        float M10 = T10*C00 + T11*C01 + T12*C02;
        float M11 = T10*C01 + T11*C11 + T12*C12;
        float M12 = T10*C02 + T11*C12 + T12*C22;

        float o00 = M00*T00 + M01*T01 + M02*T02;
        float o01 = M00*T10 + M01*T11 + M02*T12;
        float o11 = M10*T10 + M11*T11 + M12*T12;

        f32x4 v = { o00, o01, o01, o11 };
        __builtin_nontemporal_store(v,
            reinterpret_cast<f32x4*>(out + ((size_t)b*N + n)*4));
    }
}

extern "C" void kernel_launch(void* const* d_in, const int* in_sizes, int n_in,
                              void* d_out, int out_size, void* d_ws, size_t ws_size,
                              hipStream_t stream) {
    const int*   indexes = (const int*)  d_in[0];
    const float* xyz     = (const float*)d_in[1];
    const float* scales  = (const float*)d_in[2];
    const float* quats   = (const float*)d_in[3];
    const float* tf      = (const float*)d_in[4];
    const float* focal   = (const float*)d_in[5];
    const float* widths  = (const float*)d_in[6];
    float*       out     = (float*)d_out;

    int N = in_sizes[1] / 3;   // N_GAUSS
    int block = 256;
    int grid = (N + block - 1) / block;
    render_cov2d_kernel<<<grid, block, 0, stream>>>(
        indexes, xyz, scales, quats, tf, focal, widths, out, N);
}